// Round 6
// baseline (590.367 us; speedup 1.0000x reference)
//
#include <hip/hip_runtime.h>
#include <hip/hip_bf16.h>

#define B_ 8
#define N_ 1024
#define D_ 1024
#define H_ 16
#define FF_ 4096
#define TOK_ (B_*N_)

typedef __attribute__((ext_vector_type(8))) short bf16x8;
typedef __attribute__((ext_vector_type(4))) float f32x4;

typedef const __attribute__((address_space(1))) void* gc_ptr;
typedef __attribute__((address_space(3))) void* lp_ptr;

// float -> bf16 bits, round-to-nearest-even (values are finite; no NaN path needed)
__device__ __forceinline__ short f2bf(float f) {
    unsigned u = __builtin_bit_cast(unsigned, f);
    u = (u + 0x7FFFu + ((u >> 16) & 1u)) >> 16;
    return (short)u;
}

// fast erf: Abramowitz-Stegun 7.1.26, max |err| 1.5e-7 — bf16-indistinguishable
// from libm erff, ~16 VALU instrs vs ~40-80 for erff (no divergent branches).
__device__ __forceinline__ float gelu_fast(float t) {
    const float y = t * 0.70710678118654752f;
    const float a = __builtin_fabsf(y);
    const float r = __builtin_amdgcn_rcpf(__builtin_fmaf(0.3275911f, a, 1.f));
    const float p = r * (0.254829592f +
                    r * (-0.284496736f +
                    r * (1.421413741f +
                    r * (-1.453152027f +
                    r * 1.061405429f))));
    const float e = __expf(-a * a);
    float erfv = 1.f - p * e;
    erfv = __builtin_copysignf(erfv, y);
    return 0.5f * t * (1.f + erfv);
}

// ---------------------------------------------------------------------------
// fp32 -> bf16 convert (all 4 weight tensors in ONE launch), 4 elems/thread.
// ---------------------------------------------------------------------------
__global__ __launch_bounds__(256)
void cvt_all(const float* __restrict__ s0, const float* __restrict__ s1,
             const float* __restrict__ s2, const float* __restrict__ s3,
             short* __restrict__ d0, short* __restrict__ d1,
             short* __restrict__ d2, short* __restrict__ d3) {
    const int blk = blockIdx.x;
    const float* src; short* dst; int base;
    if (blk < 3072)      { src = s0; dst = d0; base = blk; }
    else if (blk < 4096) { src = s1; dst = d1; base = blk - 3072; }
    else if (blk < 8192) { src = s2; dst = d2; base = blk - 4096; }
    else                 { src = s3; dst = d3; base = blk - 8192; }
    const size_t i = ((size_t)base * 256 + threadIdx.x) * 4;
    const float4 v = *(const float4*)(src + i);
    short4 o;
    o.x = f2bf(v.x); o.y = f2bf(v.y); o.z = f2bf(v.z); o.w = f2bf(v.w);
    *(short4*)(dst + i) = o;
}

// ---------------------------------------------------------------------------
// LayerNorm over D=1024: one block per row, 256 threads, 4 floats each.
// Writes fp32 (residual path) and bf16 (GEMM input).
// ---------------------------------------------------------------------------
__global__ __launch_bounds__(256)
void ln_kernel(const float* __restrict__ in, const float* __restrict__ w,
               const float* __restrict__ bi, float* __restrict__ o32,
               short* __restrict__ obf) {
    const int row = blockIdx.x;
    const int tid = threadIdx.x;
    const float4 v = ((const float4*)(in + (size_t)row * D_))[tid];
    float s = v.x + v.y + v.z + v.w;
    float q = v.x * v.x + v.y * v.y + v.z * v.z + v.w * v.w;
#pragma unroll
    for (int off = 1; off < 64; off <<= 1) {
        s += __shfl_xor(s, off);
        q += __shfl_xor(q, off);
    }
    __shared__ float ss[4], sq[4];
    const int wave = tid >> 6, lane = tid & 63;
    if (lane == 0) { ss[wave] = s; sq[wave] = q; }
    __syncthreads();
    s = ss[0] + ss[1] + ss[2] + ss[3];
    q = sq[0] + sq[1] + sq[2] + sq[3];
    const float mu = s * (1.f / D_);
    const float var = q * (1.f / D_) - mu * mu;
    const float rs = rsqrtf(var + 1e-5f);
    const float4 wv = ((const float4*)w)[tid];
    const float4 bv = ((const float4*)bi)[tid];
    float4 o;
    o.x = (v.x - mu) * rs * wv.x + bv.x;
    o.y = (v.y - mu) * rs * wv.y + bv.y;
    o.z = (v.z - mu) * rs * wv.z + bv.z;
    o.w = (v.w - mu) * rs * wv.w + bv.w;
    ((float4*)(o32 + (size_t)row * D_))[tid] = o;
    short4 ob;
    ob.x = f2bf(o.x); ob.y = f2bf(o.y); ob.z = f2bf(o.z); ob.w = f2bf(o.w);
    *(short4*)(obf + (size_t)row * D_ + tid * 4) = ob;
}

// ---------------------------------------------------------------------------
// GEMM: C[M,Nc] = A[M,K] @ Bw[Nc,K]^T  (both bf16, K-contiguous)
// v10: per-call-site configs:
//  BN=128, NBUF=2: verified round-1 structure (32 KB LDS, __syncthreads
//          double buffer). For large-grid calls (QKV 1536 blk, lin1 2048).
//  BN=64,  NBUF=4: for the Nc=1024 low-grid latency-bound calls (proj_out,
//          lin2). 48 KB LDS -> 3 blk/CU TLP + depth-3 prefetch with COUNTED
//          vmcnt. RACE FIX vs round-3: the barrier is now
//          asm volatile("s_barrier":::"memory") + sched_barrier(0) —
//          __builtin_amdgcn_s_barrier alone is NOT a compiler memory fence,
//          so tile-t ds_reads could hoist between the lgkmcnt wait and the
//          barrier, reading rows other waves had not yet confirmed staged.
// vmcnt arithmetic (NBUF=4, BN=64): loop body has NO other VMEM ops; each
// stage() = exactly 3 global_load_lds/thread (2 A reps + 1 B rep). At top of
// iter t, stages t+1,t+2 are the only ones newer than stage(t) -> steady
// wait vmcnt(6); tail 6->3->0 via rem = T-1-t.
// Overwrite race: stage(t+3) (issued after barrier t) writes buf (t-1)&3;
// all waves' tile-(t-1) ds_reads completed before their barrier-t arrival
// (explicit lgkmcnt(0)), so the overwrite is safe. Readers of tile t+3 wait
// vmcnt(6) at iter t+3, which retires stage(t+3)'s loads (in-order retire).
// XCD-pinned tile map (xcd = lin&7), XOR chunk swizzle on staging + reads.
// MODE 0: scatter q,k -> [B,H,N,64]; v -> TRANSPOSED [B,H,64,N]
// MODE 1: out_f32 = acc + bias[col] + res[row,col]
// MODE 2: out_bf16 = gelu(acc + bias[col])   [fast-erf, 1.5e-7 accurate]
// ---------------------------------------------------------------------------
template<int MODE, int BN, int NBUF>
__global__ __launch_bounds__(256, BN == 64 ? 3 : 2)
void gemm_bt(const short* __restrict__ A, const short* __restrict__ Bw,
             const float* __restrict__ bias, const float* __restrict__ res,
             void* __restrict__ outp, int M, int Nc, int K) {
    constexpr int NJ    = BN / 32;   // j-frags per wave (4 or 2)
    constexpr int BREPS = BN / 64;   // B staging reps (2 or 1)
    const int tid  = threadIdx.x;
    const int wave = tid >> 6;
    const int lane = tid & 63;
    const int m16  = lane & 15;
    const int quad = lane >> 4;
    const int wrow = (wave >> 1) * 64;
    const int wcol = (wave & 1) * (BN / 2);

    // XCD-pinned decode (requires M/128 % 8 == 0 — true for all calls: gy=64)
    const int gy = M >> 7;             // row-tiles
    const int rowsPerX = gy >> 3;      // row-tiles per XCD
    const int lin  = blockIdx.x;
    const int xcd  = lin & 7;
    const int loc  = lin >> 3;
    const int rowL = loc % rowsPerX;
    const int colT = loc / rowsPerX;
    const int rowBase = (rowL * 8 + xcd) * 128;
    const int colBase = colT * BN;

    __shared__ short sA[NBUF][128 * 32];
    __shared__ short sB[NBUF][BN * 32];

    f32x4 acc[4][NJ];
#pragma unroll
    for (int i = 0; i < 4; ++i)
#pragma unroll
        for (int j = 0; j < NJ; ++j)
            acc[i][j] = {0.f, 0.f, 0.f, 0.f};

    const int r16 = lane >> 2;              // row within 16-row staging group
    const int c4  = lane & 3;               // LDS slot within 64B row
    const int csw = c4 ^ ((r16 >> 1) & 3);  // swizzled global chunk for this slot

    auto stage = [&](int t) {
        const int kt = t * 32;
        short* dA = sA[t & (NBUF - 1)];
        short* dB = sB[t & (NBUF - 1)];
#pragma unroll
        for (int rep = 0; rep < 2; ++rep) {
            const int tr = rep * 64 + wave * 16;
            const short* ga = A + (size_t)(rowBase + tr + r16) * K + kt + csw * 8;
            __builtin_amdgcn_global_load_lds((gc_ptr)ga, (lp_ptr)(dA + tr * 32), 16, 0, 0);
        }
#pragma unroll
        for (int rep = 0; rep < BREPS; ++rep) {
            const int tr = rep * 64 + wave * 16;
            const short* gb = Bw + (size_t)(colBase + tr + r16) * K + kt + csw * 8;
            __builtin_amdgcn_global_load_lds((gc_ptr)gb, (lp_ptr)(dB + tr * 32), 16, 0, 0);
        }
    };

    const int qsw = (quad ^ ((m16 >> 1) & 3)) * 8;  // swizzled frag-read slot

    const int T = K >> 5;
    stage(0);
    if constexpr (NBUF == 4) { stage(1); stage(2); }
    for (int t = 0; t < T; ++t) {
        if constexpr (NBUF == 4) {
            // counted wait: stage() = 3 loads; stages newer than stage(t)
            // at this point are t+1, t+2 -> 6 loads may stay outstanding.
            const int rem = T - 1 - t;
            if (rem >= 2)      asm volatile("s_waitcnt vmcnt(6)" ::: "memory");
            else if (rem == 1) asm volatile("s_waitcnt vmcnt(3)" ::: "memory");
            else               asm volatile("s_waitcnt vmcnt(0)" ::: "memory");
            asm volatile("s_waitcnt lgkmcnt(0)" ::: "memory");  // my t-1 ds_reads done
            asm volatile("s_barrier" ::: "memory");  // HW barrier + compiler fence
            __builtin_amdgcn_sched_barrier(0);       // pin: nothing crosses
            if (t + 3 < T) stage(t + 3);             // prefetch into buf (t-1)&3
        } else {
            __syncthreads();             // implicit vmcnt drain publishes tile t
            if (t + 1 < T) stage(t + 1); // prefetch next tile into other buffer
        }
        const short* cA = sA[t & (NBUF - 1)];
        const short* cB = sB[t & (NBUF - 1)];

        bf16x8 af[4], bfr[NJ];
#pragma unroll
        for (int i = 0; i < 4; ++i)
            af[i] = *(const bf16x8*)(cA + (wrow + i * 16 + m16) * 32 + qsw);
#pragma unroll
        for (int j = 0; j < NJ; ++j)
            bfr[j] = *(const bf16x8*)(cB + (wcol + j * 16 + m16) * 32 + qsw);
#pragma unroll
        for (int i = 0; i < 4; ++i)
#pragma unroll
            for (int j = 0; j < NJ; ++j)
                acc[i][j] = __builtin_amdgcn_mfma_f32_16x16x32_bf16(af[i], bfr[j], acc[i][j], 0, 0, 0);
    }

    // epilogue: C/D layout col = lane&15, row = quad*4 + r  (m89-verified)
#pragma unroll
    for (int i = 0; i < 4; ++i) {
#pragma unroll
        for (int j = 0; j < NJ; ++j) {
            const int col = colBase + wcol + j * 16 + m16;
#pragma unroll
            for (int r = 0; r < 4; ++r) {
                const int row = rowBase + wrow + i * 16 + quad * 4 + r;
                const float val = acc[i][j][r];
                if (MODE == 0) {
                    const int ci = col >> 10, hh = (col >> 6) & 15, dd = col & 63;
                    const int bb = row >> 10, nn = row & 1023;
                    size_t idx;
                    if (ci == 2)   // V transposed: [b,h,dh,N]
                        idx = (size_t)2 * ((size_t)TOK_ * 1024) +
                              ((size_t)((bb * H_ + hh) * 64 + dd)) * N_ + nn;
                    else
                        idx = (size_t)ci * ((size_t)TOK_ * 1024) +
                              ((size_t)((bb * H_ + hh) * N_ + nn)) * 64 + dd;
                    ((short*)outp)[idx] = f2bf(val);
                } else if (MODE == 1) {
                    ((float*)outp)[(size_t)row * Nc + col] =
                        val + bias[col] + res[(size_t)row * Nc + col];
                } else {
                    const float g = gelu_fast(val + bias[col]);
                    ((short*)outp)[(size_t)row * Nc + col] = f2bf(g);
                }
            }
        }
    }
}

// ---------------------------------------------------------------------------
// Flash attention v5 (unchanged; verified). 1D grid, XCD-pinned. Block = 64
// q-rows, 4 waves x 16 rows. KT=64 double-buffered K/V via global_load_lds,
// one barrier/tile, no-max softmax.
// ---------------------------------------------------------------------------
__global__ __launch_bounds__(256, 4)
void attn_kernel(const short* __restrict__ q, const short* __restrict__ k,
                 const short* __restrict__ vT, const int* __restrict__ ids,
                 short* __restrict__ outp) {
    const int tid  = threadIdx.x;
    const int wave = tid >> 6;
    const int lane = tid & 63;
    const int m    = lane & 15;
    const int quad = lane >> 4;
    const int lin  = blockIdx.x;
    const int qb   = lin >> 7;          // 16 q-blocks
    const int bhid = lin & 127;         // b*16+h
    const int b  = bhid >> 4;
    const int h  = bhid & 15;
    const int q0 = qb * 64;
    const size_t bh = ((size_t)b * H_ + h) * N_;

    __shared__ short Kb[2][4096];
    __shared__ short Vb[2][4096];
    __shared__ short Pl[4][16 * 40];   // per-wave P tile [qrow][32 keys + pad]

    const short* kbase  = k  + bh * 64;
    const short* vtbase = vT + bh * 64;   // [dh][N] for this (b,h)
    const int* idrow = ids + b * N_;

    bf16x8 aq0, aq1;
    {
        const short* qp = q + (bh + q0 + wave * 16 + m) * 64;
        aq0 = *(const bf16x8*)(qp + quad * 8);
        aq1 = *(const bf16x8*)(qp + 32 + quad * 8);
    }

    const int l4 = lane >> 2, c3 = lane & 3;     // staging: 16 rows x 4 slots
    const int csw = c3 ^ ((l4 >> 1) & 3);        // swizzled global chunk

    auto stage = [&](int t) {
        short* Kd = Kb[t & 1];
        short* Vd = Vb[t & 1];
        const int kt = t * 64;
        const int keyrow = 16 * wave + l4;      // key (for K) / dh (for V), 0..63
#pragma unroll
        for (int hh = 0; hh < 2; ++hh) {        // K: dh-half hh
            const short* gk = kbase + (size_t)(kt + keyrow) * 64 + hh * 32 + csw * 8;
            __builtin_amdgcn_global_load_lds((gc_ptr)gk,
                (lp_ptr)(Kd + hh * 2048 + 512 * wave + lane * 8), 16, 0, 0);
        }
#pragma unroll
        for (int g = 0; g < 2; ++g) {           // V: key-half g
            const short* gv = vtbase + (size_t)keyrow * N_ + kt + g * 32 + csw * 8;
            __builtin_amdgcn_global_load_lds((gc_ptr)gv,
                (lp_ptr)(Vd + g * 2048 + 512 * wave + lane * 8), 16, 0, 0);
        }
    };

    float plocal[4] = {0.f, 0.f, 0.f, 0.f};
    f32x4 o[4];
#pragma unroll
    for (int j = 0; j < 4; ++j) o[j] = {0.f, 0.f, 0.f, 0.f};

    short* pw = Pl[wave];
    const int qsw = (quad ^ ((m >> 1) & 3)) * 8;  // swizzled frag-read slot

    stage(0);
    for (int t = 0; t < 16; ++t) {
        __syncthreads();                // implicit vmcnt drain publishes tile t
        if (t < 15) stage(t + 1);       // prefetch next tile into other buffer
        const short* Ks = Kb[t & 1];
        const short* Vs = Vb[t & 1];
        const int kt = t * 64;
#pragma unroll
        for (int g = 0; g < 2; ++g) {   // two 32-key subgroups
            const float msk0 = -1e9f * (float)idrow[kt + g * 32 + m];
            const float msk1 = -1e9f * (float)idrow[kt + g * 32 + 16 + m];
            const bf16x8 b00 = *(const bf16x8*)(Ks + (g * 32 + m) * 32 + qsw);
            const bf16x8 b01 = *(const bf16x8*)(Ks + 2048 + (g * 32 + m) * 32 + qsw);
            const bf16x8 b10 = *(const bf16x8*)(Ks + (g * 32 + 16 + m) * 32 + qsw);
            const bf16x8 b11 = *(const bf16x8*)(Ks + 2048 + (g * 32 + 16 + m) * 32 + qsw);
            f32x4 s0 = {0.f, 0.f, 0.f, 0.f}, s1 = {0.f, 0.f, 0.f, 0.f};
            s0 = __builtin_amdgcn_mfma_f32_16x16x32_bf16(aq0, b00, s0, 0, 0, 0);
            s0 = __builtin_amdgcn_mfma_f32_16x16x32_bf16(aq1, b01, s0, 0, 0, 0);
            s1 = __builtin_amdgcn_mfma_f32_16x16x32_bf16(aq0, b10, s1, 0, 0, 0);
            s1 = __builtin_amdgcn_mfma_f32_16x16x32_bf16(aq1, b11, s1, 0, 0, 0);
#pragma unroll
            for (int r = 0; r < 4; ++r) {
                const float p0 = __expf((s0[r] + msk0) * 0.125f);
                const float p1 = __expf((s1[r] + msk1) * 0.125f);
                plocal[r] += p0 + p1;
                pw[(quad * 4 + r) * 40 + m]      = f2bf(p0);
                pw[(quad * 4 + r) * 40 + 16 + m] = f2bf(p1);
            }
            const bf16x8 pa = *(const bf16x8*)(pw + m * 40 + quad * 8);
#pragma unroll
            for (int j = 0; j < 4; ++j) {
                const bf16x8 bv = *(const bf16x8*)(Vs + g * 2048 + (j * 16 + m) * 32 + qsw);
                o[j] = __builtin_amdgcn_mfma_f32_16x16x32_bf16(pa, bv, o[j], 0, 0, 0);
            }
        }
    }

#pragma unroll
    for (int r = 0; r < 4; ++r) {
        float su = plocal[r];
        su += __shfl_xor(su, 1);
        su += __shfl_xor(su, 2);
        su += __shfl_xor(su, 4);
        su += __shfl_xor(su, 8);
        const float inv = 1.f / su;
        const int n = q0 + wave * 16 + quad * 4 + r;
        short* op = outp + ((size_t)(b * N_ + n)) * D_ + h * 64 + m;
#pragma unroll
        for (int j = 0; j < 4; ++j)
            op[j * 16] = f2bf(o[j][r] * inv);
    }
}

// ---------------------------------------------------------------------------
extern "C" void kernel_launch(void* const* d_in, const int* in_sizes, int n_in,
                              void* d_out, int out_size, void* d_ws, size_t ws_size,
                              hipStream_t stream) {
    const float* x   = (const float*)d_in[0];
    const int*   ids = (const int*)d_in[1];
    const float* n1w = (const float*)d_in[2];
    const float* n1b = (const float*)d_in[3];
    const float* win = (const float*)d_in[4];
    const float* wout= (const float*)d_in[5];
    const float* bout= (const float*)d_in[6];
    const float* n2w = (const float*)d_in[7];
    const float* n2b = (const float*)d_in[8];
    const float* w1  = (const float*)d_in[9];
    const float* b1  = (const float*)d_in[10];
    const float* w2  = (const float*)d_in[11];
    const float* b2  = (const float*)d_in[12];
    float* out = (float*)d_out;

    char* ws = (char*)d_ws;
    size_t off = 0;
    auto alloc = [&](size_t bytes) {
        char* p = ws + off;
        off += (bytes + 255) & ~(size_t)255;
        return p;
    };
    short* wq_b = (short*)alloc((size_t)3 * D_ * D_ * 2);       // proj_in bf16
    short* wo_b = (short*)alloc((size_t)D_ * D_ * 2);           // proj_out bf16
    short* w1_b = (short*)alloc((size_t)FF_ * D_ * 2);          // lin1 bf16
    short* w2_b = (short*)alloc((size_t)D_ * FF_ * 2);          // lin2 bf16
    float* xn32 = (float*)alloc((size_t)TOK_ * D_ * 4);         // LN1 out fp32
    short* xnb  = (short*)alloc((size_t)TOK_ * D_ * 2);         // LN1 out bf16
    short* qkv  = (short*)alloc((size_t)3 * TOK_ * D_ * 2);     // q,k [B,H,N,64]; vT [B,H,64,N]
    float* x2f  = (float*)alloc((size_t)TOK_ * D_ * 4);         // LN2 out fp32
    short* hbuf = (short*)alloc((size_t)TOK_ * FF_ * 2);        // gelu(lin1) bf16
    // aliases (lifetimes disjoint in stream order):
    short* attno = xnb;          // attention output bf16 (xn_bf16 dead after QKV gemm)
    float* x1f   = (float*)qkv;  // x1 fp32 (qkv dead after attention)
    short* x2b   = xnb;          // LN2 bf16 (attno dead after proj_out gemm)

    // 1) weights -> bf16 (single merged launch)
    cvt_all<<<12288, 256, 0, stream>>>(win, wout, w1, w2, wq_b, wo_b, w1_b, w2_b);
    // 2) LN1
    ln_kernel<<<TOK_, 256, 0, stream>>>(x, n1w, n1b, xn32, xnb);
    // 3) QKV projection — grid 1536 (6 blk/CU): BN=128 NBUF=2 (verified r1)
    gemm_bt<0, 128, 2><<<(3 * D_ / 128) * (TOK_ / 128), 256, 0, stream>>>(
        xnb, wq_b, nullptr, nullptr, qkv, TOK_, 3 * D_, D_);
    // 4) attention — 1D XCD-pinned grid
    attn_kernel<<<(N_ / 64) * H_ * B_, 256, 0, stream>>>(
        qkv, qkv + (size_t)TOK_ * D_, qkv + (size_t)2 * TOK_ * D_, ids, attno);
    // 5) out projection + bias + residual(xn) — BN=64 NBUF=4: grid 1024, 3 blk/CU
    gemm_bt<1, 64, 4><<<(D_ / 64) * (TOK_ / 128), 256, 0, stream>>>(
        attno, wo_b, bout, xn32, x1f, TOK_, D_, D_);
    // 6) LN2
    ln_kernel<<<TOK_, 256, 0, stream>>>(x1f, n2w, n2b, x2f, x2b);
    // 7) lin1 + bias + GELU — grid 2048 (8 blk/CU): BN=128 NBUF=2 (verified r1)
    gemm_bt<2, 128, 2><<<(FF_ / 128) * (TOK_ / 128), 256, 0, stream>>>(
        x2b, w1_b, b1, nullptr, hbuf, TOK_, FF_, D_);
    // 8) lin2 + bias + residual(x2) — BN=64 NBUF=4: grid 1024, 3 blk/CU
    gemm_bt<1, 64, 4><<<(D_ / 64) * (TOK_ / 128), 256, 0, stream>>>(
        hbuf, w2_b, b2, x2f, out, TOK_, D_, FF_);
}

// Round 8
// 519.626 us; speedup vs baseline: 1.1361x; 1.1361x over previous
//
#include <hip/hip_runtime.h>
#include <hip/hip_bf16.h>

#define B_ 8
#define N_ 1024
#define D_ 1024
#define H_ 16
#define FF_ 4096
#define TOK_ (B_*N_)

typedef __attribute__((ext_vector_type(8))) short bf16x8;
typedef __attribute__((ext_vector_type(4))) float f32x4;

typedef const __attribute__((address_space(1))) void* gc_ptr;
typedef __attribute__((address_space(3))) void* lp_ptr;

// float -> bf16 bits, round-to-nearest-even (values are finite; no NaN path needed)
__device__ __forceinline__ short f2bf(float f) {
    unsigned u = __builtin_bit_cast(unsigned, f);
    u = (u + 0x7FFFu + ((u >> 16) & 1u)) >> 16;
    return (short)u;
}
__device__ __forceinline__ float bf2f(short s) {
    unsigned u = ((unsigned)(unsigned short)s) << 16;
    return __builtin_bit_cast(float, u);
}

// fast erf: Abramowitz-Stegun 7.1.26, max |err| 1.5e-7 — bf16-indistinguishable
// from libm erff, ~16 VALU instrs vs ~40-80 for erff (no divergent branches).
__device__ __forceinline__ float gelu_fast(float t) {
    const float y = t * 0.70710678118654752f;
    const float a = __builtin_fabsf(y);
    const float r = __builtin_amdgcn_rcpf(__builtin_fmaf(0.3275911f, a, 1.f));
    const float p = r * (0.254829592f +
                    r * (-0.284496736f +
                    r * (1.421413741f +
                    r * (-1.453152027f +
                    r * 1.061405429f))));
    const float e = __expf(-a * a);
    float erfv = 1.f - p * e;
    erfv = __builtin_copysignf(erfv, y);
    return 0.5f * t * (1.f + erfv);
}

// ---------------------------------------------------------------------------
// Merged head-of-stream kernel: blocks [0,12288) convert the 4 weight
// tensors fp32->bf16 (4 elems/thread); blocks [12288,20480) do LayerNorm1
// (one block per row). Both memory-bound and independent — merging overlaps
// them on HBM BW and saves a launch gap.
// ---------------------------------------------------------------------------
__global__ __launch_bounds__(256)
void cvt_ln(const float* __restrict__ s0, const float* __restrict__ s1,
            const float* __restrict__ s2, const float* __restrict__ s3,
            short* __restrict__ d0, short* __restrict__ d1,
            short* __restrict__ d2, short* __restrict__ d3,
            const float* __restrict__ x, const float* __restrict__ w,
            const float* __restrict__ bi, float* __restrict__ o32,
            short* __restrict__ obf) {
    const int blk = blockIdx.x;
    const int tid = threadIdx.x;
    if (blk < 12288) {
        const float* src; short* dst; int base;
        if (blk < 3072)      { src = s0; dst = d0; base = blk; }
        else if (blk < 4096) { src = s1; dst = d1; base = blk - 3072; }
        else if (blk < 8192) { src = s2; dst = d2; base = blk - 4096; }
        else                 { src = s3; dst = d3; base = blk - 8192; }
        const size_t i = ((size_t)base * 256 + tid) * 4;
        const float4 v = *(const float4*)(src + i);
        short4 o;
        o.x = f2bf(v.x); o.y = f2bf(v.y); o.z = f2bf(v.z); o.w = f2bf(v.w);
        *(short4*)(dst + i) = o;
        return;
    }
    const int row = blk - 12288;
    const float4 v = ((const float4*)(x + (size_t)row * D_))[tid];
    float s = v.x + v.y + v.z + v.w;
    float q = v.x * v.x + v.y * v.y + v.z * v.z + v.w * v.w;
#pragma unroll
    for (int off = 1; off < 64; off <<= 1) {
        s += __shfl_xor(s, off);
        q += __shfl_xor(q, off);
    }
    __shared__ float ss[4], sq[4];
    const int wave = tid >> 6, lane = tid & 63;
    if (lane == 0) { ss[wave] = s; sq[wave] = q; }
    __syncthreads();
    s = ss[0] + ss[1] + ss[2] + ss[3];
    q = sq[0] + sq[1] + sq[2] + sq[3];
    const float mu = s * (1.f / D_);
    const float var = q * (1.f / D_) - mu * mu;
    const float rs = rsqrtf(var + 1e-5f);
    const float4 wv = ((const float4*)w)[tid];
    const float4 bv = ((const float4*)bi)[tid];
    float4 o;
    o.x = (v.x - mu) * rs * wv.x + bv.x;
    o.y = (v.y - mu) * rs * wv.y + bv.y;
    o.z = (v.z - mu) * rs * wv.z + bv.z;
    o.w = (v.w - mu) * rs * wv.w + bv.w;
    ((float4*)(o32 + (size_t)row * D_))[tid] = o;
    short4 ob;
    ob.x = f2bf(o.x); ob.y = f2bf(o.y); ob.z = f2bf(o.z); ob.w = f2bf(o.w);
    *(short4*)(obf + (size_t)row * D_ + tid * 4) = ob;
}

// ---------------------------------------------------------------------------
// LayerNorm over D=1024: one block per row (used for LN2).
// ---------------------------------------------------------------------------
__global__ __launch_bounds__(256)
void ln_kernel(const float* __restrict__ in, const float* __restrict__ w,
               const float* __restrict__ bi, float* __restrict__ o32,
               short* __restrict__ obf) {
    const int row = blockIdx.x;
    const int tid = threadIdx.x;
    const float4 v = ((const float4*)(in + (size_t)row * D_))[tid];
    float s = v.x + v.y + v.z + v.w;
    float q = v.x * v.x + v.y * v.y + v.z * v.z + v.w * v.w;
#pragma unroll
    for (int off = 1; off < 64; off <<= 1) {
        s += __shfl_xor(s, off);
        q += __shfl_xor(q, off);
    }
    __shared__ float ss[4], sq[4];
    const int wave = tid >> 6, lane = tid & 63;
    if (lane == 0) { ss[wave] = s; sq[wave] = q; }
    __syncthreads();
    s = ss[0] + ss[1] + ss[2] + ss[3];
    q = sq[0] + sq[1] + sq[2] + sq[3];
    const float mu = s * (1.f / D_);
    const float var = q * (1.f / D_) - mu * mu;
    const float rs = rsqrtf(var + 1e-5f);
    const float4 wv = ((const float4*)w)[tid];
    const float4 bv = ((const float4*)bi)[tid];
    float4 o;
    o.x = (v.x - mu) * rs * wv.x + bv.x;
    o.y = (v.y - mu) * rs * wv.y + bv.y;
    o.z = (v.z - mu) * rs * wv.z + bv.z;
    o.w = (v.w - mu) * rs * wv.w + bv.w;
    ((float4*)(o32 + (size_t)row * D_))[tid] = o;
    short4 ob;
    ob.x = f2bf(o.x); ob.y = f2bf(o.y); ob.z = f2bf(o.z); ob.w = f2bf(o.w);
    *(short4*)(obf + (size_t)row * D_ + tid * 4) = ob;
}

// ---------------------------------------------------------------------------
// GEMM: C[M,Nc] = A[M,K] @ Bw[Nc,K]^T  (both bf16, K-contiguous)
// v11: VERIFIED round-1 sync structure ONLY (2-buffer __syncthreads double
// buffer). Counted-vmcnt pipelining is permanently abandoned on this
// structure (r2/r3/r5/r6: race or regression — matches the guide's
// regime-gate: T3/T4 require a full 8-phase schedule, not a graft).
//  BN=128: 128x128 tile, 32 KB LDS, 4 waves each 64x64. QKV/proj_out/lin1.
//  BN=64:  128x64 tile, 24 KB LDS, 4 blk/CU (launch_bounds 4). lin2 only
//          (grid 512->1024; measured r4: 113->106 us).
// XCD-pinned tile map (xcd = lin&7), XOR chunk swizzle on staging + reads.
// MODE 0: scatter q,k -> [B,H,N,64]; v -> TRANSPOSED [B,H,64,N]
// MODE 1: out_f32 = acc + bias[col] + res[row,col]
// MODE 2: out_bf16 = gelu(acc + bias[col])   [fast-erf, 1.5e-7 accurate]
// ---------------------------------------------------------------------------
template<int MODE, int BN>
__global__ __launch_bounds__(256, BN == 64 ? 4 : 2)
void gemm_bt(const short* __restrict__ A, const short* __restrict__ Bw,
             const float* __restrict__ bias, const float* __restrict__ res,
             void* __restrict__ outp, int M, int Nc, int K) {
    constexpr int NJ    = BN / 32;   // j-frags per wave (4 or 2)
    constexpr int BREPS = BN / 64;   // B staging reps (2 or 1)
    const int tid  = threadIdx.x;
    const int wave = tid >> 6;
    const int lane = tid & 63;
    const int m16  = lane & 15;
    const int quad = lane >> 4;
    const int wrow = (wave >> 1) * 64;
    const int wcol = (wave & 1) * (BN / 2);

    // XCD-pinned decode (requires M/128 % 8 == 0 — true for all calls: gy=64)
    const int gy = M >> 7;             // row-tiles
    const int rowsPerX = gy >> 3;      // row-tiles per XCD
    const int lin  = blockIdx.x;
    const int xcd  = lin & 7;
    const int loc  = lin >> 3;
    const int rowL = loc % rowsPerX;
    const int colT = loc / rowsPerX;
    const int rowBase = (rowL * 8 + xcd) * 128;
    const int colBase = colT * BN;

    __shared__ short sA[2][128 * 32];
    __shared__ short sB[2][BN * 32];

    f32x4 acc[4][NJ];
#pragma unroll
    for (int i = 0; i < 4; ++i)
#pragma unroll
        for (int j = 0; j < NJ; ++j)
            acc[i][j] = {0.f, 0.f, 0.f, 0.f};

    const int r16 = lane >> 2;              // row within 16-row staging group
    const int c4  = lane & 3;               // LDS slot within 64B row
    const int csw = c4 ^ ((r16 >> 1) & 3);  // swizzled global chunk for this slot

    auto stage = [&](int t) {
        const int kt = t * 32;
        short* dA = sA[t & 1];
        short* dB = sB[t & 1];
#pragma unroll
        for (int rep = 0; rep < 2; ++rep) {
            const int tr = rep * 64 + wave * 16;
            const short* ga = A + (size_t)(rowBase + tr + r16) * K + kt + csw * 8;
            __builtin_amdgcn_global_load_lds((gc_ptr)ga, (lp_ptr)(dA + tr * 32), 16, 0, 0);
        }
#pragma unroll
        for (int rep = 0; rep < BREPS; ++rep) {
            const int tr = rep * 64 + wave * 16;
            const short* gb = Bw + (size_t)(colBase + tr + r16) * K + kt + csw * 8;
            __builtin_amdgcn_global_load_lds((gc_ptr)gb, (lp_ptr)(dB + tr * 32), 16, 0, 0);
        }
    };

    const int qsw = (quad ^ ((m16 >> 1) & 3)) * 8;  // swizzled frag-read slot

    const int T = K >> 5;
    stage(0);
    for (int t = 0; t < T; ++t) {
        __syncthreads();             // implicit vmcnt drain publishes tile t
        if (t + 1 < T) stage(t + 1); // prefetch next tile into other buffer
        const short* cA = sA[t & 1];
        const short* cB = sB[t & 1];

        bf16x8 af[4], bfr[NJ];
#pragma unroll
        for (int i = 0; i < 4; ++i)
            af[i] = *(const bf16x8*)(cA + (wrow + i * 16 + m16) * 32 + qsw);
#pragma unroll
        for (int j = 0; j < NJ; ++j)
            bfr[j] = *(const bf16x8*)(cB + (wcol + j * 16 + m16) * 32 + qsw);
#pragma unroll
        for (int i = 0; i < 4; ++i)
#pragma unroll
            for (int j = 0; j < NJ; ++j)
                acc[i][j] = __builtin_amdgcn_mfma_f32_16x16x32_bf16(af[i], bfr[j], acc[i][j], 0, 0, 0);
    }

    // epilogue: C/D layout col = lane&15, row = quad*4 + r  (m89-verified)
#pragma unroll
    for (int i = 0; i < 4; ++i) {
#pragma unroll
        for (int j = 0; j < NJ; ++j) {
            const int col = colBase + wcol + j * 16 + m16;
#pragma unroll
            for (int r = 0; r < 4; ++r) {
                const int row = rowBase + wrow + i * 16 + quad * 4 + r;
                const float val = acc[i][j][r];
                if (MODE == 0) {
                    const int ci = col >> 10, hh = (col >> 6) & 15, dd = col & 63;
                    const int bb = row >> 10, nn = row & 1023;
                    size_t idx;
                    if (ci == 2)   // V transposed: [b,h,dh,N]
                        idx = (size_t)2 * ((size_t)TOK_ * 1024) +
                              ((size_t)((bb * H_ + hh) * 64 + dd)) * N_ + nn;
                    else
                        idx = (size_t)ci * ((size_t)TOK_ * 1024) +
                              ((size_t)((bb * H_ + hh) * N_ + nn)) * 64 + dd;
                    ((short*)outp)[idx] = f2bf(val);
                } else if (MODE == 1) {
                    ((float*)outp)[(size_t)row * Nc + col] =
                        val + bias[col] + res[(size_t)row * Nc + col];
                } else {
                    const float g = gelu_fast(val + bias[col]);
                    ((short*)outp)[(size_t)row * Nc + col] = f2bf(g);
                }
            }
        }
    }
}

// ---------------------------------------------------------------------------
// Flash attention v6: v5 + mask row preloaded into LDS (bf16, 2 KB) at block
// start — removes 64 in-loop scalar global loads per wave from the critical
// path between barriers. LDS/block = 16+16+5+2 = 39.9 KB -> still 4 blk/CU.
// The t=0 __syncthreads publishes Msk along with the first staged tile.
// ---------------------------------------------------------------------------
__global__ __launch_bounds__(256, 4)
void attn_kernel(const short* __restrict__ q, const short* __restrict__ k,
                 const short* __restrict__ vT, const int* __restrict__ ids,
                 short* __restrict__ outp) {
    const int tid  = threadIdx.x;
    const int wave = tid >> 6;
    const int lane = tid & 63;
    const int m    = lane & 15;
    const int quad = lane >> 4;
    const int lin  = blockIdx.x;
    const int qb   = lin >> 7;          // 16 q-blocks
    const int bhid = lin & 127;         // b*16+h
    const int b  = bhid >> 4;
    const int h  = bhid & 15;
    const int q0 = qb * 64;
    const size_t bh = ((size_t)b * H_ + h) * N_;

    __shared__ short Kb[2][4096];
    __shared__ short Vb[2][4096];
    __shared__ short Pl[4][16 * 40];   // per-wave P tile [qrow][32 keys + pad]
    __shared__ short Msk[N_];          // bf16 of -1e9*ids[b][n]

    const short* kbase  = k  + bh * 64;
    const short* vtbase = vT + bh * 64;   // [dh][N] for this (b,h)
    const int* idrow = ids + b * N_;

    // mask preload: 256 threads x 4 ints
    {
        const int4 iv = ((const int4*)idrow)[tid];
        short4 mv;
        mv.x = f2bf(-1e9f * (float)iv.x);
        mv.y = f2bf(-1e9f * (float)iv.y);
        mv.z = f2bf(-1e9f * (float)iv.z);
        mv.w = f2bf(-1e9f * (float)iv.w);
        *(short4*)(Msk + tid * 4) = mv;
    }

    bf16x8 aq0, aq1;
    {
        const short* qp = q + (bh + q0 + wave * 16 + m) * 64;
        aq0 = *(const bf16x8*)(qp + quad * 8);
        aq1 = *(const bf16x8*)(qp + 32 + quad * 8);
    }

    const int l4 = lane >> 2, c3 = lane & 3;     // staging: 16 rows x 4 slots
    const int csw = c3 ^ ((l4 >> 1) & 3);        // swizzled global chunk

    auto stage = [&](int t) {
        short* Kd = Kb[t & 1];
        short* Vd = Vb[t & 1];
        const int kt = t * 64;
        const int keyrow = 16 * wave + l4;      // key (for K) / dh (for V), 0..63
#pragma unroll
        for (int hh = 0; hh < 2; ++hh) {        // K: dh-half hh
            const short* gk = kbase + (size_t)(kt + keyrow) * 64 + hh * 32 + csw * 8;
            __builtin_amdgcn_global_load_lds((gc_ptr)gk,
                (lp_ptr)(Kd + hh * 2048 + 512 * wave + lane * 8), 16, 0, 0);
        }
#pragma unroll
        for (int g = 0; g < 2; ++g) {           // V: key-half g
            const short* gv = vtbase + (size_t)keyrow * N_ + kt + g * 32 + csw * 8;
            __builtin_amdgcn_global_load_lds((gc_ptr)gv,
                (lp_ptr)(Vd + g * 2048 + 512 * wave + lane * 8), 16, 0, 0);
        }
    };

    float plocal[4] = {0.f, 0.f, 0.f, 0.f};
    f32x4 o[4];
#pragma unroll
    for (int j = 0; j < 4; ++j) o[j] = {0.f, 0.f, 0.f, 0.f};

    short* pw = Pl[wave];
    const int qsw = (quad ^ ((m >> 1) & 3)) * 8;  // swizzled frag-read slot

    stage(0);
    for (int t = 0; t < 16; ++t) {
        __syncthreads();                // publishes tile t (and Msk at t=0)
        if (t < 15) stage(t + 1);       // prefetch next tile into other buffer
        const short* Ks = Kb[t & 1];
        const short* Vs = Vb[t & 1];
        const int kt = t * 64;
#pragma unroll
        for (int g = 0; g < 2; ++g) {   // two 32-key subgroups
            const float msk0 = bf2f(Msk[kt + g * 32 + m]);
            const float msk1 = bf2f(Msk[kt + g * 32 + 16 + m]);
            const bf16x8 b00 = *(const bf16x8*)(Ks + (g * 32 + m) * 32 + qsw);
            const bf16x8 b01 = *(const bf16x8*)(Ks + 2048 + (g * 32 + m) * 32 + qsw);
            const bf16x8 b10 = *(const bf16x8*)(Ks + (g * 32 + 16 + m) * 32 + qsw);
            const bf16x8 b11 = *(const bf16x8*)(Ks + 2048 + (g * 32 + 16 + m) * 32 + qsw);
            f32x4 s0 = {0.f, 0.f, 0.f, 0.f}, s1 = {0.f, 0.f, 0.f, 0.f};
            s0 = __builtin_amdgcn_mfma_f32_16x16x32_bf16(aq0, b00, s0, 0, 0, 0);
            s0 = __builtin_amdgcn_mfma_f32_16x16x32_bf16(aq1, b01, s0, 0, 0, 0);
            s1 = __builtin_amdgcn_mfma_f32_16x16x32_bf16(aq0, b10, s1, 0, 0, 0);
            s1 = __builtin_amdgcn_mfma_f32_16x16x32_bf16(aq1, b11, s1, 0, 0, 0);
#pragma unroll
            for (int r = 0; r < 4; ++r) {
                const float p0 = __expf((s0[r] + msk0) * 0.125f);
                const float p1 = __expf((s1[r] + msk1) * 0.125f);
                plocal[r] += p0 + p1;
                pw[(quad * 4 + r) * 40 + m]      = f2bf(p0);
                pw[(quad * 4 + r) * 40 + 16 + m] = f2bf(p1);
            }
            const bf16x8 pa = *(const bf16x8*)(pw + m * 40 + quad * 8);
#pragma unroll
            for (int j = 0; j < 4; ++j) {
                const bf16x8 bv = *(const bf16x8*)(Vs + g * 2048 + (j * 16 + m) * 32 + qsw);
                o[j] = __builtin_amdgcn_mfma_f32_16x16x32_bf16(pa, bv, o[j], 0, 0, 0);
            }
        }
    }

#pragma unroll
    for (int r = 0; r < 4; ++r) {
        float su = plocal[r];
        su += __shfl_xor(su, 1);
        su += __shfl_xor(su, 2);
        su += __shfl_xor(su, 4);
        su += __shfl_xor(su, 8);
        const float inv = 1.f / su;
        const int n = q0 + wave * 16 + quad * 4 + r;
        short* op = outp + ((size_t)(b * N_ + n)) * D_ + h * 64 + m;
#pragma unroll
        for (int j = 0; j < 4; ++j)
            op[j * 16] = f2bf(o[j][r] * inv);
    }
}

// ---------------------------------------------------------------------------
extern "C" void kernel_launch(void* const* d_in, const int* in_sizes, int n_in,
                              void* d_out, int out_size, void* d_ws, size_t ws_size,
                              hipStream_t stream) {
    const float* x   = (const float*)d_in[0];
    const int*   ids = (const int*)d_in[1];
    const float* n1w = (const float*)d_in[2];
    const float* n1b = (const float*)d_in[3];
    const float* win = (const float*)d_in[4];
    const float* wout= (const float*)d_in[5];
    const float* bout= (const float*)d_in[6];
    const float* n2w = (const float*)d_in[7];
    const float* n2b = (const float*)d_in[8];
    const float* w1  = (const float*)d_in[9];
    const float* b1  = (const float*)d_in[10];
    const float* w2  = (const float*)d_in[11];
    const float* b2  = (const float*)d_in[12];
    float* out = (float*)d_out;

    char* ws = (char*)d_ws;
    size_t off = 0;
    auto alloc = [&](size_t bytes) {
        char* p = ws + off;
        off += (bytes + 255) & ~(size_t)255;
        return p;
    };
    short* wq_b = (short*)alloc((size_t)3 * D_ * D_ * 2);       // proj_in bf16
    short* wo_b = (short*)alloc((size_t)D_ * D_ * 2);           // proj_out bf16
    short* w1_b = (short*)alloc((size_t)FF_ * D_ * 2);          // lin1 bf16
    short* w2_b = (short*)alloc((size_t)D_ * FF_ * 2);          // lin2 bf16
    float* xn32 = (float*)alloc((size_t)TOK_ * D_ * 4);         // LN1 out fp32
    short* xnb  = (short*)alloc((size_t)TOK_ * D_ * 2);         // LN1 out bf16
    short* qkv  = (short*)alloc((size_t)3 * TOK_ * D_ * 2);     // q,k [B,H,N,64]; vT [B,H,64,N]
    float* x2f  = (float*)alloc((size_t)TOK_ * D_ * 4);         // LN2 out fp32
    short* hbuf = (short*)alloc((size_t)TOK_ * FF_ * 2);        // gelu(lin1) bf16
    // aliases (lifetimes disjoint in stream order):
    short* attno = xnb;          // attention output bf16 (xn_bf16 dead after QKV gemm)
    float* x1f   = (float*)qkv;  // x1 fp32 (qkv dead after attention)
    short* x2b   = xnb;          // LN2 bf16 (attno dead after proj_out gemm)

    // 1) weights -> bf16 + LN1, one merged launch (12288 cvt + 8192 LN blocks)
    cvt_ln<<<20480, 256, 0, stream>>>(win, wout, w1, w2, wq_b, wo_b, w1_b, w2_b,
                                      x, n1w, n1b, xn32, xnb);
    // 2) QKV projection — grid 1536 (6 blk/CU): BN=128
    gemm_bt<0, 128><<<(3 * D_ / 128) * (TOK_ / 128), 256, 0, stream>>>(
        xnb, wq_b, nullptr, nullptr, qkv, TOK_, 3 * D_, D_);
    // 3) attention — 1D XCD-pinned grid, mask preloaded in LDS
    attn_kernel<<<(N_ / 64) * H_ * B_, 256, 0, stream>>>(
        qkv, qkv + (size_t)TOK_ * D_, qkv + (size_t)2 * TOK_ * D_, ids, attno);
    // 4) out projection + bias + residual(xn) — BN=128, grid 512
    gemm_bt<1, 128><<<(D_ / 128) * (TOK_ / 128), 256, 0, stream>>>(
        attno, wo_b, bout, xn32, x1f, TOK_, D_, D_);
    // 5) LN2
    ln_kernel<<<TOK_, 256, 0, stream>>>(x1f, n2w, n2b, x2f, x2b);
    // 6) lin1 + bias + GELU — grid 2048 (8 blk/CU): BN=128
    gemm_bt<2, 128><<<(FF_ / 128) * (TOK_ / 128), 256, 0, stream>>>(
        x2b, w1_b, b1, nullptr, hbuf, TOK_, FF_, D_);
    // 7) lin2 + bias + residual(x2) — BN=64: grid 1024 (4 blk/CU, r4-measured win)
    gemm_bt<1, 64><<<(D_ / 64) * (TOK_ / 128), 256, 0, stream>>>(
        hbuf, w2_b, b2, x2f, out, TOK_, D_, FF_);
}

// Round 9
// 498.341 us; speedup vs baseline: 1.1847x; 1.0427x over previous
//
#include <hip/hip_runtime.h>
#include <hip/hip_bf16.h>

#define B_ 8
#define N_ 1024
#define D_ 1024
#define H_ 16
#define FF_ 4096
#define TOK_ (B_*N_)

typedef __attribute__((ext_vector_type(8))) short bf16x8;
typedef __attribute__((ext_vector_type(4))) float f32x4;

typedef const __attribute__((address_space(1))) void* gc_ptr;
typedef __attribute__((address_space(3))) void* lp_ptr;

// float -> bf16 bits, round-to-nearest-even (values are finite; no NaN path needed)
__device__ __forceinline__ short f2bf(float f) {
    unsigned u = __builtin_bit_cast(unsigned, f);
    u = (u + 0x7FFFu + ((u >> 16) & 1u)) >> 16;
    return (short)u;
}
__device__ __forceinline__ float bf2f(short s) {
    unsigned u = ((unsigned)(unsigned short)s) << 16;
    return __builtin_bit_cast(float, u);
}

// fast erf: Abramowitz-Stegun 7.1.26, max |err| 1.5e-7 — bf16-indistinguishable
// from libm erff, ~16 VALU instrs vs ~40-80 for erff (no divergent branches).
__device__ __forceinline__ float gelu_fast(float t) {
    const float y = t * 0.70710678118654752f;
    const float a = __builtin_fabsf(y);
    const float r = __builtin_amdgcn_rcpf(__builtin_fmaf(0.3275911f, a, 1.f));
    const float p = r * (0.254829592f +
                    r * (-0.284496736f +
                    r * (1.421413741f +
                    r * (-1.453152027f +
                    r * 1.061405429f))));
    const float e = __expf(-a * a);
    float erfv = 1.f - p * e;
    erfv = __builtin_copysignf(erfv, y);
    return 0.5f * t * (1.f + erfv);
}

// ---------------------------------------------------------------------------
// Merged head-of-stream kernel: blocks [0,12288) convert the 4 weight
// tensors fp32->bf16 (4 elems/thread); blocks [12288,20480) do LayerNorm1,
// bf16 output ONLY (the fp32 copy was only ever used as proj_out residual —
// now read from the bf16 xnb, saving 32 MB write + 16 MB read).
// ---------------------------------------------------------------------------
__global__ __launch_bounds__(256)
void cvt_ln(const float* __restrict__ s0, const float* __restrict__ s1,
            const float* __restrict__ s2, const float* __restrict__ s3,
            short* __restrict__ d0, short* __restrict__ d1,
            short* __restrict__ d2, short* __restrict__ d3,
            const float* __restrict__ x, const float* __restrict__ w,
            const float* __restrict__ bi, short* __restrict__ obf) {
    const int blk = blockIdx.x;
    const int tid = threadIdx.x;
    if (blk < 12288) {
        const float* src; short* dst; int base;
        if (blk < 3072)      { src = s0; dst = d0; base = blk; }
        else if (blk < 4096) { src = s1; dst = d1; base = blk - 3072; }
        else if (blk < 8192) { src = s2; dst = d2; base = blk - 4096; }
        else                 { src = s3; dst = d3; base = blk - 8192; }
        const size_t i = ((size_t)base * 256 + tid) * 4;
        const float4 v = *(const float4*)(src + i);
        short4 o;
        o.x = f2bf(v.x); o.y = f2bf(v.y); o.z = f2bf(v.z); o.w = f2bf(v.w);
        *(short4*)(dst + i) = o;
        return;
    }
    const int row = blk - 12288;
    const float4 v = ((const float4*)(x + (size_t)row * D_))[tid];
    float s = v.x + v.y + v.z + v.w;
    float q = v.x * v.x + v.y * v.y + v.z * v.z + v.w * v.w;
#pragma unroll
    for (int off = 1; off < 64; off <<= 1) {
        s += __shfl_xor(s, off);
        q += __shfl_xor(q, off);
    }
    __shared__ float ss[4], sq[4];
    const int wave = tid >> 6, lane = tid & 63;
    if (lane == 0) { ss[wave] = s; sq[wave] = q; }
    __syncthreads();
    s = ss[0] + ss[1] + ss[2] + ss[3];
    q = sq[0] + sq[1] + sq[2] + sq[3];
    const float mu = s * (1.f / D_);
    const float var = q * (1.f / D_) - mu * mu;
    const float rs = rsqrtf(var + 1e-5f);
    const float4 wv = ((const float4*)w)[tid];
    const float4 bv = ((const float4*)bi)[tid];
    short4 ob;
    ob.x = f2bf((v.x - mu) * rs * wv.x + bv.x);
    ob.y = f2bf((v.y - mu) * rs * wv.y + bv.y);
    ob.z = f2bf((v.z - mu) * rs * wv.z + bv.z);
    ob.w = f2bf((v.w - mu) * rs * wv.w + bv.w);
    *(short4*)(obf + (size_t)row * D_ + tid * 4) = ob;
}

// ---------------------------------------------------------------------------
// LayerNorm over D=1024, bf16 input -> bf16 output (LN2). One block per row.
// bf16 x1 input adds ~0.4% per-element rounding — absmax budget 0.127 vs
// current 0.031, and mean/var over 1024 elems averages the noise down.
// ---------------------------------------------------------------------------
__global__ __launch_bounds__(256)
void lnb_kernel(const short* __restrict__ in, const float* __restrict__ w,
                const float* __restrict__ bi, short* __restrict__ obf) {
    const int row = blockIdx.x;
    const int tid = threadIdx.x;
    const short4 v4 = ((const short4*)(in + (size_t)row * D_))[tid];
    const float a0 = bf2f(v4.x), a1 = bf2f(v4.y), a2 = bf2f(v4.z), a3 = bf2f(v4.w);
    float s = a0 + a1 + a2 + a3;
    float q = a0 * a0 + a1 * a1 + a2 * a2 + a3 * a3;
#pragma unroll
    for (int off = 1; off < 64; off <<= 1) {
        s += __shfl_xor(s, off);
        q += __shfl_xor(q, off);
    }
    __shared__ float ss[4], sq[4];
    const int wave = tid >> 6, lane = tid & 63;
    if (lane == 0) { ss[wave] = s; sq[wave] = q; }
    __syncthreads();
    s = ss[0] + ss[1] + ss[2] + ss[3];
    q = sq[0] + sq[1] + sq[2] + sq[3];
    const float mu = s * (1.f / D_);
    const float var = q * (1.f / D_) - mu * mu;
    const float rs = rsqrtf(var + 1e-5f);
    const float4 wv = ((const float4*)w)[tid];
    const float4 bv = ((const float4*)bi)[tid];
    short4 ob;
    ob.x = f2bf((a0 - mu) * rs * wv.x + bv.x);
    ob.y = f2bf((a1 - mu) * rs * wv.y + bv.y);
    ob.z = f2bf((a2 - mu) * rs * wv.z + bv.z);
    ob.w = f2bf((a3 - mu) * rs * wv.w + bv.w);
    *(short4*)(obf + (size_t)row * D_ + tid * 4) = ob;
}

// ---------------------------------------------------------------------------
// GEMM: C[M,Nc] = A[M,K] @ Bw[Nc,K]^T  (both bf16, K-contiguous)
// v12: verified 2-buffer __syncthreads structure only (counted-vmcnt family
// permanently abandoned: r2/r3/r5/r6). BN per call site (128; 64 for lin2 —
// r4/r8-measured win). Residuals are now bf16 (res is const short*).
// MODE 0: scatter q,k -> [B,H,N,64]; v -> TRANSPOSED [B,H,64,N]  (bf16 out)
// MODE 1: out_f32  = acc + bias[col] + bf2f(res[row,col])        (final lin2)
// MODE 2: out_bf16 = gelu(acc + bias[col])                       (lin1)
// MODE 3: out_bf16 = acc + bias[col] + bf2f(res[row,col])        (proj_out)
// XCD-pinned tile map (xcd = lin&7), XOR chunk swizzle on staging + reads.
// ---------------------------------------------------------------------------
template<int MODE, int BN>
__global__ __launch_bounds__(256, BN == 64 ? 4 : 2)
void gemm_bt(const short* __restrict__ A, const short* __restrict__ Bw,
             const float* __restrict__ bias, const short* __restrict__ res,
             void* __restrict__ outp, int M, int Nc, int K) {
    constexpr int NJ    = BN / 32;   // j-frags per wave (4 or 2)
    constexpr int BREPS = BN / 64;   // B staging reps (2 or 1)
    const int tid  = threadIdx.x;
    const int wave = tid >> 6;
    const int lane = tid & 63;
    const int m16  = lane & 15;
    const int quad = lane >> 4;
    const int wrow = (wave >> 1) * 64;
    const int wcol = (wave & 1) * (BN / 2);

    // XCD-pinned decode (requires M/128 % 8 == 0 — true for all calls: gy=64)
    const int gy = M >> 7;             // row-tiles
    const int rowsPerX = gy >> 3;      // row-tiles per XCD
    const int lin  = blockIdx.x;
    const int xcd  = lin & 7;
    const int loc  = lin >> 3;
    const int rowL = loc % rowsPerX;
    const int colT = loc / rowsPerX;
    const int rowBase = (rowL * 8 + xcd) * 128;
    const int colBase = colT * BN;

    __shared__ short sA[2][128 * 32];
    __shared__ short sB[2][BN * 32];

    f32x4 acc[4][NJ];
#pragma unroll
    for (int i = 0; i < 4; ++i)
#pragma unroll
        for (int j = 0; j < NJ; ++j)
            acc[i][j] = {0.f, 0.f, 0.f, 0.f};

    const int r16 = lane >> 2;              // row within 16-row staging group
    const int c4  = lane & 3;               // LDS slot within 64B row
    const int csw = c4 ^ ((r16 >> 1) & 3);  // swizzled global chunk for this slot

    auto stage = [&](int t) {
        const int kt = t * 32;
        short* dA = sA[t & 1];
        short* dB = sB[t & 1];
#pragma unroll
        for (int rep = 0; rep < 2; ++rep) {
            const int tr = rep * 64 + wave * 16;
            const short* ga = A + (size_t)(rowBase + tr + r16) * K + kt + csw * 8;
            __builtin_amdgcn_global_load_lds((gc_ptr)ga, (lp_ptr)(dA + tr * 32), 16, 0, 0);
        }
#pragma unroll
        for (int rep = 0; rep < BREPS; ++rep) {
            const int tr = rep * 64 + wave * 16;
            const short* gb = Bw + (size_t)(colBase + tr + r16) * K + kt + csw * 8;
            __builtin_amdgcn_global_load_lds((gc_ptr)gb, (lp_ptr)(dB + tr * 32), 16, 0, 0);
        }
    };

    const int qsw = (quad ^ ((m16 >> 1) & 3)) * 8;  // swizzled frag-read slot

    const int T = K >> 5;
    stage(0);
    for (int t = 0; t < T; ++t) {
        __syncthreads();             // implicit vmcnt drain publishes tile t
        if (t + 1 < T) stage(t + 1); // prefetch next tile into other buffer
        const short* cA = sA[t & 1];
        const short* cB = sB[t & 1];

        bf16x8 af[4], bfr[NJ];
#pragma unroll
        for (int i = 0; i < 4; ++i)
            af[i] = *(const bf16x8*)(cA + (wrow + i * 16 + m16) * 32 + qsw);
#pragma unroll
        for (int j = 0; j < NJ; ++j)
            bfr[j] = *(const bf16x8*)(cB + (wcol + j * 16 + m16) * 32 + qsw);
#pragma unroll
        for (int i = 0; i < 4; ++i)
#pragma unroll
            for (int j = 0; j < NJ; ++j)
                acc[i][j] = __builtin_amdgcn_mfma_f32_16x16x32_bf16(af[i], bfr[j], acc[i][j], 0, 0, 0);
    }

    // epilogue: C/D layout col = lane&15, row = quad*4 + r  (m89-verified)
#pragma unroll
    for (int i = 0; i < 4; ++i) {
#pragma unroll
        for (int j = 0; j < NJ; ++j) {
            const int col = colBase + wcol + j * 16 + m16;
#pragma unroll
            for (int r = 0; r < 4; ++r) {
                const int row = rowBase + wrow + i * 16 + quad * 4 + r;
                const float val = acc[i][j][r];
                if (MODE == 0) {
                    const int ci = col >> 10, hh = (col >> 6) & 15, dd = col & 63;
                    const int bb = row >> 10, nn = row & 1023;
                    size_t idx;
                    if (ci == 2)   // V transposed: [b,h,dh,N]
                        idx = (size_t)2 * ((size_t)TOK_ * 1024) +
                              ((size_t)((bb * H_ + hh) * 64 + dd)) * N_ + nn;
                    else
                        idx = (size_t)ci * ((size_t)TOK_ * 1024) +
                              ((size_t)((bb * H_ + hh) * N_ + nn)) * 64 + dd;
                    ((short*)outp)[idx] = f2bf(val);
                } else if (MODE == 1) {
                    ((float*)outp)[(size_t)row * Nc + col] =
                        val + bias[col] + bf2f(res[(size_t)row * Nc + col]);
                } else if (MODE == 2) {
                    const float g = gelu_fast(val + bias[col]);
                    ((short*)outp)[(size_t)row * Nc + col] = f2bf(g);
                } else {  // MODE 3
                    const float v3 = val + bias[col] + bf2f(res[(size_t)row * Nc + col]);
                    ((short*)outp)[(size_t)row * Nc + col] = f2bf(v3);
                }
            }
        }
    }
}

// ---------------------------------------------------------------------------
// Flash attention v6 (r8-verified): mask row preloaded into LDS (bf16, 2 KB).
// 1D grid, XCD-pinned. Block = 64 q-rows, 4 waves x 16 rows. KT=64
// double-buffered K/V via global_load_lds, one barrier/tile, no-max softmax.
// ---------------------------------------------------------------------------
__global__ __launch_bounds__(256, 4)
void attn_kernel(const short* __restrict__ q, const short* __restrict__ k,
                 const short* __restrict__ vT, const int* __restrict__ ids,
                 short* __restrict__ outp) {
    const int tid  = threadIdx.x;
    const int wave = tid >> 6;
    const int lane = tid & 63;
    const int m    = lane & 15;
    const int quad = lane >> 4;
    const int lin  = blockIdx.x;
    const int qb   = lin >> 7;          // 16 q-blocks
    const int bhid = lin & 127;         // b*16+h
    const int b  = bhid >> 4;
    const int h  = bhid & 15;
    const int q0 = qb * 64;
    const size_t bh = ((size_t)b * H_ + h) * N_;

    __shared__ short Kb[2][4096];
    __shared__ short Vb[2][4096];
    __shared__ short Pl[4][16 * 40];   // per-wave P tile [qrow][32 keys + pad]
    __shared__ short Msk[N_];          // bf16 of -1e9*ids[b][n]

    const short* kbase  = k  + bh * 64;
    const short* vtbase = vT + bh * 64;   // [dh][N] for this (b,h)
    const int* idrow = ids + b * N_;

    // mask preload: 256 threads x 4 ints
    {
        const int4 iv = ((const int4*)idrow)[tid];
        short4 mv;
        mv.x = f2bf(-1e9f * (float)iv.x);
        mv.y = f2bf(-1e9f * (float)iv.y);
        mv.z = f2bf(-1e9f * (float)iv.z);
        mv.w = f2bf(-1e9f * (float)iv.w);
        *(short4*)(Msk + tid * 4) = mv;
    }

    bf16x8 aq0, aq1;
    {
        const short* qp = q + (bh + q0 + wave * 16 + m) * 64;
        aq0 = *(const bf16x8*)(qp + quad * 8);
        aq1 = *(const bf16x8*)(qp + 32 + quad * 8);
    }

    const int l4 = lane >> 2, c3 = lane & 3;     // staging: 16 rows x 4 slots
    const int csw = c3 ^ ((l4 >> 1) & 3);        // swizzled global chunk

    auto stage = [&](int t) {
        short* Kd = Kb[t & 1];
        short* Vd = Vb[t & 1];
        const int kt = t * 64;
        const int keyrow = 16 * wave + l4;      // key (for K) / dh (for V), 0..63
#pragma unroll
        for (int hh = 0; hh < 2; ++hh) {        // K: dh-half hh
            const short* gk = kbase + (size_t)(kt + keyrow) * 64 + hh * 32 + csw * 8;
            __builtin_amdgcn_global_load_lds((gc_ptr)gk,
                (lp_ptr)(Kd + hh * 2048 + 512 * wave + lane * 8), 16, 0, 0);
        }
#pragma unroll
        for (int g = 0; g < 2; ++g) {           // V: key-half g
            const short* gv = vtbase + (size_t)keyrow * N_ + kt + g * 32 + csw * 8;
            __builtin_amdgcn_global_load_lds((gc_ptr)gv,
                (lp_ptr)(Vd + g * 2048 + 512 * wave + lane * 8), 16, 0, 0);
        }
    };

    float plocal[4] = {0.f, 0.f, 0.f, 0.f};
    f32x4 o[4];
#pragma unroll
    for (int j = 0; j < 4; ++j) o[j] = {0.f, 0.f, 0.f, 0.f};

    short* pw = Pl[wave];
    const int qsw = (quad ^ ((m >> 1) & 3)) * 8;  // swizzled frag-read slot

    stage(0);
    for (int t = 0; t < 16; ++t) {
        __syncthreads();                // publishes tile t (and Msk at t=0)
        if (t < 15) stage(t + 1);       // prefetch next tile into other buffer
        const short* Ks = Kb[t & 1];
        const short* Vs = Vb[t & 1];
        const int kt = t * 64;
#pragma unroll
        for (int g = 0; g < 2; ++g) {   // two 32-key subgroups
            const float msk0 = bf2f(Msk[kt + g * 32 + m]);
            const float msk1 = bf2f(Msk[kt + g * 32 + 16 + m]);
            const bf16x8 b00 = *(const bf16x8*)(Ks + (g * 32 + m) * 32 + qsw);
            const bf16x8 b01 = *(const bf16x8*)(Ks + 2048 + (g * 32 + m) * 32 + qsw);
            const bf16x8 b10 = *(const bf16x8*)(Ks + (g * 32 + 16 + m) * 32 + qsw);
            const bf16x8 b11 = *(const bf16x8*)(Ks + 2048 + (g * 32 + 16 + m) * 32 + qsw);
            f32x4 s0 = {0.f, 0.f, 0.f, 0.f}, s1 = {0.f, 0.f, 0.f, 0.f};
            s0 = __builtin_amdgcn_mfma_f32_16x16x32_bf16(aq0, b00, s0, 0, 0, 0);
            s0 = __builtin_amdgcn_mfma_f32_16x16x32_bf16(aq1, b01, s0, 0, 0, 0);
            s1 = __builtin_amdgcn_mfma_f32_16x16x32_bf16(aq0, b10, s1, 0, 0, 0);
            s1 = __builtin_amdgcn_mfma_f32_16x16x32_bf16(aq1, b11, s1, 0, 0, 0);
#pragma unroll
            for (int r = 0; r < 4; ++r) {
                const float p0 = __expf((s0[r] + msk0) * 0.125f);
                const float p1 = __expf((s1[r] + msk1) * 0.125f);
                plocal[r] += p0 + p1;
                pw[(quad * 4 + r) * 40 + m]      = f2bf(p0);
                pw[(quad * 4 + r) * 40 + 16 + m] = f2bf(p1);
            }
            const bf16x8 pa = *(const bf16x8*)(pw + m * 40 + quad * 8);
#pragma unroll
            for (int j = 0; j < 4; ++j) {
                const bf16x8 bv = *(const bf16x8*)(Vs + g * 2048 + (j * 16 + m) * 32 + qsw);
                o[j] = __builtin_amdgcn_mfma_f32_16x16x32_bf16(pa, bv, o[j], 0, 0, 0);
            }
        }
    }

#pragma unroll
    for (int r = 0; r < 4; ++r) {
        float su = plocal[r];
        su += __shfl_xor(su, 1);
        su += __shfl_xor(su, 2);
        su += __shfl_xor(su, 4);
        su += __shfl_xor(su, 8);
        const float inv = 1.f / su;
        const int n = q0 + wave * 16 + quad * 4 + r;
        short* op = outp + ((size_t)(b * N_ + n)) * D_ + h * 64 + m;
#pragma unroll
        for (int j = 0; j < 4; ++j)
            op[j * 16] = f2bf(o[j][r] * inv);
    }
}

// ---------------------------------------------------------------------------
extern "C" void kernel_launch(void* const* d_in, const int* in_sizes, int n_in,
                              void* d_out, int out_size, void* d_ws, size_t ws_size,
                              hipStream_t stream) {
    const float* x   = (const float*)d_in[0];
    const int*   ids = (const int*)d_in[1];
    const float* n1w = (const float*)d_in[2];
    const float* n1b = (const float*)d_in[3];
    const float* win = (const float*)d_in[4];
    const float* wout= (const float*)d_in[5];
    const float* bout= (const float*)d_in[6];
    const float* n2w = (const float*)d_in[7];
    const float* n2b = (const float*)d_in[8];
    const float* w1  = (const float*)d_in[9];
    const float* b1  = (const float*)d_in[10];
    const float* w2  = (const float*)d_in[11];
    const float* b2  = (const float*)d_in[12];
    float* out = (float*)d_out;

    char* ws = (char*)d_ws;
    size_t off = 0;
    auto alloc = [&](size_t bytes) {
        char* p = ws + off;
        off += (bytes + 255) & ~(size_t)255;
        return p;
    };
    short* wq_b  = (short*)alloc((size_t)3 * D_ * D_ * 2);      // proj_in bf16
    short* wo_b  = (short*)alloc((size_t)D_ * D_ * 2);          // proj_out bf16
    short* w1_b  = (short*)alloc((size_t)FF_ * D_ * 2);         // lin1 bf16
    short* w2_b  = (short*)alloc((size_t)D_ * FF_ * 2);         // lin2 bf16
    short* xnb   = (short*)alloc((size_t)TOK_ * D_ * 2);        // LN1 out bf16 (lives to proj_out res)
    short* qkv   = (short*)alloc((size_t)3 * TOK_ * D_ * 2);    // q,k [B,H,N,64]; vT [B,H,64,N]
    short* attno = (short*)alloc((size_t)TOK_ * D_ * 2);        // attention out bf16
    short* hbuf  = (short*)alloc((size_t)TOK_ * FF_ * 2);       // gelu(lin1) bf16
    // aliases (lifetimes disjoint in stream order):
    short* x1b = qkv;     // x1 bf16 (qkv dead after attention)
    short* x2b = attno;   // LN2 out bf16 (attno dead after proj_out)

    // 1) weights -> bf16 + LN1 (bf16-only out), one merged launch
    cvt_ln<<<20480, 256, 0, stream>>>(win, wout, w1, w2, wq_b, wo_b, w1_b, w2_b,
                                      x, n1w, n1b, xnb);
    // 2) QKV projection — grid 1536 (6 blk/CU): BN=128
    gemm_bt<0, 128><<<(3 * D_ / 128) * (TOK_ / 128), 256, 0, stream>>>(
        xnb, wq_b, nullptr, nullptr, qkv, TOK_, 3 * D_, D_);
    // 3) attention — 1D XCD-pinned grid, mask preloaded in LDS
    attn_kernel<<<(N_ / 64) * H_ * B_, 256, 0, stream>>>(
        qkv, qkv + (size_t)TOK_ * D_, qkv + (size_t)2 * TOK_ * D_, ids, attno);
    // 4) out projection + bias + residual(xn bf16) -> x1 bf16 — BN=128, grid 512
    gemm_bt<3, 128><<<(D_ / 128) * (TOK_ / 128), 256, 0, stream>>>(
        attno, wo_b, bout, xnb, x1b, TOK_, D_, D_);
    // 5) LN2 (bf16 in -> bf16 out)
    lnb_kernel<<<TOK_, 256, 0, stream>>>(x1b, n2w, n2b, x2b);
    // 6) lin1 + bias + GELU — grid 2048 (8 blk/CU): BN=128
    gemm_bt<2, 128><<<(FF_ / 128) * (TOK_ / 128), 256, 0, stream>>>(
        x2b, w1_b, b1, nullptr, hbuf, TOK_, FF_, D_);
    // 7) lin2 + bias + residual(x2 bf16) -> out fp32 — BN=64: grid 1024 (4 blk/CU)
    gemm_bt<1, 64><<<(D_ / 64) * (TOK_ / 128), 256, 0, stream>>>(
        hbuf, w2_b, b2, x2b, out, TOK_, D_, FF_);
}

// Round 10
// 493.220 us; speedup vs baseline: 1.1970x; 1.0104x over previous
//
#include <hip/hip_runtime.h>
#include <hip/hip_bf16.h>

#define B_ 8
#define N_ 1024
#define D_ 1024
#define H_ 16
#define FF_ 4096
#define TOK_ (B_*N_)

typedef __attribute__((ext_vector_type(8))) short bf16x8;
typedef __attribute__((ext_vector_type(4))) float f32x4;

typedef const __attribute__((address_space(1))) void* gc_ptr;
typedef __attribute__((address_space(3))) void* lp_ptr;

// float -> bf16 bits, round-to-nearest-even (values are finite; no NaN path needed)
__device__ __forceinline__ short f2bf(float f) {
    unsigned u = __builtin_bit_cast(unsigned, f);
    u = (u + 0x7FFFu + ((u >> 16) & 1u)) >> 16;
    return (short)u;
}
__device__ __forceinline__ float bf2f(short s) {
    unsigned u = ((unsigned)(unsigned short)s) << 16;
    return __builtin_bit_cast(float, u);
}

// fast erf: Abramowitz-Stegun 7.1.26, max |err| 1.5e-7 — bf16-indistinguishable
// from libm erff, ~16 VALU instrs vs ~40-80 for erff (no divergent branches).
__device__ __forceinline__ float gelu_fast(float t) {
    const float y = t * 0.70710678118654752f;
    const float a = __builtin_fabsf(y);
    const float r = __builtin_amdgcn_rcpf(__builtin_fmaf(0.3275911f, a, 1.f));
    const float p = r * (0.254829592f +
                    r * (-0.284496736f +
                    r * (1.421413741f +
                    r * (-1.453152027f +
                    r * 1.061405429f))));
    const float e = __expf(-a * a);
    float erfv = 1.f - p * e;
    erfv = __builtin_copysignf(erfv, y);
    return 0.5f * t * (1.f + erfv);
}

// ---------------------------------------------------------------------------
// Merged head-of-stream kernel: blocks [0,12288) convert the 4 weight
// tensors fp32->bf16 (4 elems/thread); blocks [12288,20480) do LayerNorm1,
// bf16 output only (proj_out residual reads the bf16 copy).
// ---------------------------------------------------------------------------
__global__ __launch_bounds__(256)
void cvt_ln(const float* __restrict__ s0, const float* __restrict__ s1,
            const float* __restrict__ s2, const float* __restrict__ s3,
            short* __restrict__ d0, short* __restrict__ d1,
            short* __restrict__ d2, short* __restrict__ d3,
            const float* __restrict__ x, const float* __restrict__ w,
            const float* __restrict__ bi, short* __restrict__ obf) {
    const int blk = blockIdx.x;
    const int tid = threadIdx.x;
    if (blk < 12288) {
        const float* src; short* dst; int base;
        if (blk < 3072)      { src = s0; dst = d0; base = blk; }
        else if (blk < 4096) { src = s1; dst = d1; base = blk - 3072; }
        else if (blk < 8192) { src = s2; dst = d2; base = blk - 4096; }
        else                 { src = s3; dst = d3; base = blk - 8192; }
        const size_t i = ((size_t)base * 256 + tid) * 4;
        const float4 v = *(const float4*)(src + i);
        short4 o;
        o.x = f2bf(v.x); o.y = f2bf(v.y); o.z = f2bf(v.z); o.w = f2bf(v.w);
        *(short4*)(dst + i) = o;
        return;
    }
    const int row = blk - 12288;
    const float4 v = ((const float4*)(x + (size_t)row * D_))[tid];
    float s = v.x + v.y + v.z + v.w;
    float q = v.x * v.x + v.y * v.y + v.z * v.z + v.w * v.w;
#pragma unroll
    for (int off = 1; off < 64; off <<= 1) {
        s += __shfl_xor(s, off);
        q += __shfl_xor(q, off);
    }
    __shared__ float ss[4], sq[4];
    const int wave = tid >> 6, lane = tid & 63;
    if (lane == 0) { ss[wave] = s; sq[wave] = q; }
    __syncthreads();
    s = ss[0] + ss[1] + ss[2] + ss[3];
    q = sq[0] + sq[1] + sq[2] + sq[3];
    const float mu = s * (1.f / D_);
    const float var = q * (1.f / D_) - mu * mu;
    const float rs = rsqrtf(var + 1e-5f);
    const float4 wv = ((const float4*)w)[tid];
    const float4 bv = ((const float4*)bi)[tid];
    short4 ob;
    ob.x = f2bf((v.x - mu) * rs * wv.x + bv.x);
    ob.y = f2bf((v.y - mu) * rs * wv.y + bv.y);
    ob.z = f2bf((v.z - mu) * rs * wv.z + bv.z);
    ob.w = f2bf((v.w - mu) * rs * wv.w + bv.w);
    *(short4*)(obf + (size_t)row * D_ + tid * 4) = ob;
}

// ---------------------------------------------------------------------------
// LayerNorm over D=1024, bf16 in -> bf16 out (LN2). One block per row.
// ---------------------------------------------------------------------------
__global__ __launch_bounds__(256)
void lnb_kernel(const short* __restrict__ in, const float* __restrict__ w,
                const float* __restrict__ bi, short* __restrict__ obf) {
    const int row = blockIdx.x;
    const int tid = threadIdx.x;
    const short4 v4 = ((const short4*)(in + (size_t)row * D_))[tid];
    const float a0 = bf2f(v4.x), a1 = bf2f(v4.y), a2 = bf2f(v4.z), a3 = bf2f(v4.w);
    float s = a0 + a1 + a2 + a3;
    float q = a0 * a0 + a1 * a1 + a2 * a2 + a3 * a3;
#pragma unroll
    for (int off = 1; off < 64; off <<= 1) {
        s += __shfl_xor(s, off);
        q += __shfl_xor(q, off);
    }
    __shared__ float ss[4], sq[4];
    const int wave = tid >> 6, lane = tid & 63;
    if (lane == 0) { ss[wave] = s; sq[wave] = q; }
    __syncthreads();
    s = ss[0] + ss[1] + ss[2] + ss[3];
    q = sq[0] + sq[1] + sq[2] + sq[3];
    const float mu = s * (1.f / D_);
    const float var = q * (1.f / D_) - mu * mu;
    const float rs = rsqrtf(var + 1e-5f);
    const float4 wv = ((const float4*)w)[tid];
    const float4 bv = ((const float4*)bi)[tid];
    short4 ob;
    ob.x = f2bf((a0 - mu) * rs * wv.x + bv.x);
    ob.y = f2bf((a1 - mu) * rs * wv.y + bv.y);
    ob.z = f2bf((a2 - mu) * rs * wv.z + bv.z);
    ob.w = f2bf((a3 - mu) * rs * wv.w + bv.w);
    *(short4*)(obf + (size_t)row * D_ + tid * 4) = ob;
}

// ---------------------------------------------------------------------------
// GEMM: C[M,Nc] = A[M,K] @ Bw[Nc,K]^T  (both bf16, K-contiguous)
// v13: verified 2-buffer __syncthreads structure only (counted-vmcnt family
// permanently abandoned: r2/r3/r5/r6 — matches guide regime-gate).
//  BN=128: 128x128 tile, 32 KB LDS (5 blk/CU). QKV, lin1.
//  BN=64:  128x64 tile, 24 KB LDS, 4 blk/CU. lin2 (r4/r8/r9-verified) and
//          NOW proj_out too — same M=8192/Nc=1024 grid-starvation shape
//          (grid 512 -> 1024 doubles resident blocks).
// Residuals bf16 (res is const short*).
// MODE 0: scatter q,k -> [B,H,N,64]; v -> TRANSPOSED [B,H,64,N]  (bf16 out)
// MODE 1: out_f32  = acc + bias[col] + bf2f(res[row,col])        (final lin2)
// MODE 2: out_bf16 = gelu(acc + bias[col])                       (lin1)
// MODE 3: out_bf16 = acc + bias[col] + bf2f(res[row,col])        (proj_out)
// XCD-pinned tile map (xcd = lin&7), XOR chunk swizzle on staging + reads.
// ---------------------------------------------------------------------------
template<int MODE, int BN>
__global__ __launch_bounds__(256, BN == 64 ? 4 : 2)
void gemm_bt(const short* __restrict__ A, const short* __restrict__ Bw,
             const float* __restrict__ bias, const short* __restrict__ res,
             void* __restrict__ outp, int M, int Nc, int K) {
    constexpr int NJ    = BN / 32;   // j-frags per wave (4 or 2)
    constexpr int BREPS = BN / 64;   // B staging reps (2 or 1)
    const int tid  = threadIdx.x;
    const int wave = tid >> 6;
    const int lane = tid & 63;
    const int m16  = lane & 15;
    const int quad = lane >> 4;
    const int wrow = (wave >> 1) * 64;
    const int wcol = (wave & 1) * (BN / 2);

    // XCD-pinned decode (requires M/128 % 8 == 0 — true for all calls: gy=64)
    const int gy = M >> 7;             // row-tiles
    const int rowsPerX = gy >> 3;      // row-tiles per XCD
    const int lin  = blockIdx.x;
    const int xcd  = lin & 7;
    const int loc  = lin >> 3;
    const int rowL = loc % rowsPerX;
    const int colT = loc / rowsPerX;
    const int rowBase = (rowL * 8 + xcd) * 128;
    const int colBase = colT * BN;

    __shared__ short sA[2][128 * 32];
    __shared__ short sB[2][BN * 32];

    f32x4 acc[4][NJ];
#pragma unroll
    for (int i = 0; i < 4; ++i)
#pragma unroll
        for (int j = 0; j < NJ; ++j)
            acc[i][j] = {0.f, 0.f, 0.f, 0.f};

    const int r16 = lane >> 2;              // row within 16-row staging group
    const int c4  = lane & 3;               // LDS slot within 64B row
    const int csw = c4 ^ ((r16 >> 1) & 3);  // swizzled global chunk for this slot

    auto stage = [&](int t) {
        const int kt = t * 32;
        short* dA = sA[t & 1];
        short* dB = sB[t & 1];
#pragma unroll
        for (int rep = 0; rep < 2; ++rep) {
            const int tr = rep * 64 + wave * 16;
            const short* ga = A + (size_t)(rowBase + tr + r16) * K + kt + csw * 8;
            __builtin_amdgcn_global_load_lds((gc_ptr)ga, (lp_ptr)(dA + tr * 32), 16, 0, 0);
        }
#pragma unroll
        for (int rep = 0; rep < BREPS; ++rep) {
            const int tr = rep * 64 + wave * 16;
            const short* gb = Bw + (size_t)(colBase + tr + r16) * K + kt + csw * 8;
            __builtin_amdgcn_global_load_lds((gc_ptr)gb, (lp_ptr)(dB + tr * 32), 16, 0, 0);
        }
    };

    const int qsw = (quad ^ ((m16 >> 1) & 3)) * 8;  // swizzled frag-read slot

    const int T = K >> 5;
    stage(0);
    for (int t = 0; t < T; ++t) {
        __syncthreads();             // implicit vmcnt drain publishes tile t
        if (t + 1 < T) stage(t + 1); // prefetch next tile into other buffer
        const short* cA = sA[t & 1];
        const short* cB = sB[t & 1];

        bf16x8 af[4], bfr[NJ];
#pragma unroll
        for (int i = 0; i < 4; ++i)
            af[i] = *(const bf16x8*)(cA + (wrow + i * 16 + m16) * 32 + qsw);
#pragma unroll
        for (int j = 0; j < NJ; ++j)
            bfr[j] = *(const bf16x8*)(cB + (wcol + j * 16 + m16) * 32 + qsw);
#pragma unroll
        for (int i = 0; i < 4; ++i)
#pragma unroll
            for (int j = 0; j < NJ; ++j)
                acc[i][j] = __builtin_amdgcn_mfma_f32_16x16x32_bf16(af[i], bfr[j], acc[i][j], 0, 0, 0);
    }

    // epilogue: C/D layout col = lane&15, row = quad*4 + r  (m89-verified)
#pragma unroll
    for (int i = 0; i < 4; ++i) {
#pragma unroll
        for (int j = 0; j < NJ; ++j) {
            const int col = colBase + wcol + j * 16 + m16;
#pragma unroll
            for (int r = 0; r < 4; ++r) {
                const int row = rowBase + wrow + i * 16 + quad * 4 + r;
                const float val = acc[i][j][r];
                if (MODE == 0) {
                    const int ci = col >> 10, hh = (col >> 6) & 15, dd = col & 63;
                    const int bb = row >> 10, nn = row & 1023;
                    size_t idx;
                    if (ci == 2)   // V transposed: [b,h,dh,N]
                        idx = (size_t)2 * ((size_t)TOK_ * 1024) +
                              ((size_t)((bb * H_ + hh) * 64 + dd)) * N_ + nn;
                    else
                        idx = (size_t)ci * ((size_t)TOK_ * 1024) +
                              ((size_t)((bb * H_ + hh) * N_ + nn)) * 64 + dd;
                    ((short*)outp)[idx] = f2bf(val);
                } else if (MODE == 1) {
                    ((float*)outp)[(size_t)row * Nc + col] =
                        val + bias[col] + bf2f(res[(size_t)row * Nc + col]);
                } else if (MODE == 2) {
                    const float g = gelu_fast(val + bias[col]);
                    ((short*)outp)[(size_t)row * Nc + col] = f2bf(g);
                } else {  // MODE 3
                    const float v3 = val + bias[col] + bf2f(res[(size_t)row * Nc + col]);
                    ((short*)outp)[(size_t)row * Nc + col] = f2bf(v3);
                }
            }
        }
    }
}

// ---------------------------------------------------------------------------
// Flash attention v7: v6 + s_setprio(1) around the MFMA clusters (T5 —
// measured +4-7% on attn with independent blocks per CU, m191; our 4 blk/CU
// are independent so the CU scheduler can favor MFMA-entering waves over
// other blocks' staging). Runtime hint only — no sync-semantics change.
// ---------------------------------------------------------------------------
__global__ __launch_bounds__(256, 4)
void attn_kernel(const short* __restrict__ q, const short* __restrict__ k,
                 const short* __restrict__ vT, const int* __restrict__ ids,
                 short* __restrict__ outp) {
    const int tid  = threadIdx.x;
    const int wave = tid >> 6;
    const int lane = tid & 63;
    const int m    = lane & 15;
    const int quad = lane >> 4;
    const int lin  = blockIdx.x;
    const int qb   = lin >> 7;          // 16 q-blocks
    const int bhid = lin & 127;         // b*16+h
    const int b  = bhid >> 4;
    const int h  = bhid & 15;
    const int q0 = qb * 64;
    const size_t bh = ((size_t)b * H_ + h) * N_;

    __shared__ short Kb[2][4096];
    __shared__ short Vb[2][4096];
    __shared__ short Pl[4][16 * 40];   // per-wave P tile [qrow][32 keys + pad]
    __shared__ short Msk[N_];          // bf16 of -1e9*ids[b][n]

    const short* kbase  = k  + bh * 64;
    const short* vtbase = vT + bh * 64;   // [dh][N] for this (b,h)
    const int* idrow = ids + b * N_;

    // mask preload: 256 threads x 4 ints
    {
        const int4 iv = ((const int4*)idrow)[tid];
        short4 mv;
        mv.x = f2bf(-1e9f * (float)iv.x);
        mv.y = f2bf(-1e9f * (float)iv.y);
        mv.z = f2bf(-1e9f * (float)iv.z);
        mv.w = f2bf(-1e9f * (float)iv.w);
        *(short4*)(Msk + tid * 4) = mv;
    }

    bf16x8 aq0, aq1;
    {
        const short* qp = q + (bh + q0 + wave * 16 + m) * 64;
        aq0 = *(const bf16x8*)(qp + quad * 8);
        aq1 = *(const bf16x8*)(qp + 32 + quad * 8);
    }

    const int l4 = lane >> 2, c3 = lane & 3;     // staging: 16 rows x 4 slots
    const int csw = c3 ^ ((l4 >> 1) & 3);        // swizzled global chunk

    auto stage = [&](int t) {
        short* Kd = Kb[t & 1];
        short* Vd = Vb[t & 1];
        const int kt = t * 64;
        const int keyrow = 16 * wave + l4;      // key (for K) / dh (for V), 0..63
#pragma unroll
        for (int hh = 0; hh < 2; ++hh) {        // K: dh-half hh
            const short* gk = kbase + (size_t)(kt + keyrow) * 64 + hh * 32 + csw * 8;
            __builtin_amdgcn_global_load_lds((gc_ptr)gk,
                (lp_ptr)(Kd + hh * 2048 + 512 * wave + lane * 8), 16, 0, 0);
        }
#pragma unroll
        for (int g = 0; g < 2; ++g) {           // V: key-half g
            const short* gv = vtbase + (size_t)keyrow * N_ + kt + g * 32 + csw * 8;
            __builtin_amdgcn_global_load_lds((gc_ptr)gv,
                (lp_ptr)(Vd + g * 2048 + 512 * wave + lane * 8), 16, 0, 0);
        }
    };

    float plocal[4] = {0.f, 0.f, 0.f, 0.f};
    f32x4 o[4];
#pragma unroll
    for (int j = 0; j < 4; ++j) o[j] = {0.f, 0.f, 0.f, 0.f};

    short* pw = Pl[wave];
    const int qsw = (quad ^ ((m >> 1) & 3)) * 8;  // swizzled frag-read slot

    stage(0);
    for (int t = 0; t < 16; ++t) {
        __syncthreads();                // publishes tile t (and Msk at t=0)
        if (t < 15) stage(t + 1);       // prefetch next tile into other buffer
        const short* Ks = Kb[t & 1];
        const short* Vs = Vb[t & 1];
        const int kt = t * 64;
#pragma unroll
        for (int g = 0; g < 2; ++g) {   // two 32-key subgroups
            const float msk0 = bf2f(Msk[kt + g * 32 + m]);
            const float msk1 = bf2f(Msk[kt + g * 32 + 16 + m]);
            const bf16x8 b00 = *(const bf16x8*)(Ks + (g * 32 + m) * 32 + qsw);
            const bf16x8 b01 = *(const bf16x8*)(Ks + 2048 + (g * 32 + m) * 32 + qsw);
            const bf16x8 b10 = *(const bf16x8*)(Ks + (g * 32 + 16 + m) * 32 + qsw);
            const bf16x8 b11 = *(const bf16x8*)(Ks + 2048 + (g * 32 + 16 + m) * 32 + qsw);
            f32x4 s0 = {0.f, 0.f, 0.f, 0.f}, s1 = {0.f, 0.f, 0.f, 0.f};
            __builtin_amdgcn_s_setprio(1);
            s0 = __builtin_amdgcn_mfma_f32_16x16x32_bf16(aq0, b00, s0, 0, 0, 0);
            s0 = __builtin_amdgcn_mfma_f32_16x16x32_bf16(aq1, b01, s0, 0, 0, 0);
            s1 = __builtin_amdgcn_mfma_f32_16x16x32_bf16(aq0, b10, s1, 0, 0, 0);
            s1 = __builtin_amdgcn_mfma_f32_16x16x32_bf16(aq1, b11, s1, 0, 0, 0);
            __builtin_amdgcn_s_setprio(0);
#pragma unroll
            for (int r = 0; r < 4; ++r) {
                const float p0 = __expf((s0[r] + msk0) * 0.125f);
                const float p1 = __expf((s1[r] + msk1) * 0.125f);
                plocal[r] += p0 + p1;
                pw[(quad * 4 + r) * 40 + m]      = f2bf(p0);
                pw[(quad * 4 + r) * 40 + 16 + m] = f2bf(p1);
            }
            const bf16x8 pa = *(const bf16x8*)(pw + m * 40 + quad * 8);
            __builtin_amdgcn_s_setprio(1);
#pragma unroll
            for (int j = 0; j < 4; ++j) {
                const bf16x8 bv = *(const bf16x8*)(Vs + g * 2048 + (j * 16 + m) * 32 + qsw);
                o[j] = __builtin_amdgcn_mfma_f32_16x16x32_bf16(pa, bv, o[j], 0, 0, 0);
            }
            __builtin_amdgcn_s_setprio(0);
        }
    }

#pragma unroll
    for (int r = 0; r < 4; ++r) {
        float su = plocal[r];
        su += __shfl_xor(su, 1);
        su += __shfl_xor(su, 2);
        su += __shfl_xor(su, 4);
        su += __shfl_xor(su, 8);
        const float inv = 1.f / su;
        const int n = q0 + wave * 16 + quad * 4 + r;
        short* op = outp + ((size_t)(b * N_ + n)) * D_ + h * 64 + m;
#pragma unroll
        for (int j = 0; j < 4; ++j)
            op[j * 16] = f2bf(o[j][r] * inv);
    }
}

// ---------------------------------------------------------------------------
extern "C" void kernel_launch(void* const* d_in, const int* in_sizes, int n_in,
                              void* d_out, int out_size, void* d_ws, size_t ws_size,
                              hipStream_t stream) {
    const float* x   = (const float*)d_in[0];
    const int*   ids = (const int*)d_in[1];
    const float* n1w = (const float*)d_in[2];
    const float* n1b = (const float*)d_in[3];
    const float* win = (const float*)d_in[4];
    const float* wout= (const float*)d_in[5];
    const float* bout= (const float*)d_in[6];
    const float* n2w = (const float*)d_in[7];
    const float* n2b = (const float*)d_in[8];
    const float* w1  = (const float*)d_in[9];
    const float* b1  = (const float*)d_in[10];
    const float* w2  = (const float*)d_in[11];
    const float* b2  = (const float*)d_in[12];
    float* out = (float*)d_out;

    char* ws = (char*)d_ws;
    size_t off = 0;
    auto alloc = [&](size_t bytes) {
        char* p = ws + off;
        off += (bytes + 255) & ~(size_t)255;
        return p;
    };
    short* wq_b  = (short*)alloc((size_t)3 * D_ * D_ * 2);      // proj_in bf16
    short* wo_b  = (short*)alloc((size_t)D_ * D_ * 2);          // proj_out bf16
    short* w1_b  = (short*)alloc((size_t)FF_ * D_ * 2);         // lin1 bf16
    short* w2_b  = (short*)alloc((size_t)D_ * FF_ * 2);         // lin2 bf16
    short* xnb   = (short*)alloc((size_t)TOK_ * D_ * 2);        // LN1 out bf16 (lives to proj_out res)
    short* qkv   = (short*)alloc((size_t)3 * TOK_ * D_ * 2);    // q,k [B,H,N,64]; vT [B,H,64,N]
    short* attno = (short*)alloc((size_t)TOK_ * D_ * 2);        // attention out bf16
    short* hbuf  = (short*)alloc((size_t)TOK_ * FF_ * 2);       // gelu(lin1) bf16
    // aliases (lifetimes disjoint in stream order):
    short* x1b = qkv;     // x1 bf16 (qkv dead after attention)
    short* x2b = attno;   // LN2 out bf16 (attno dead after proj_out)

    // 1) weights -> bf16 + LN1 (bf16-only out), one merged launch
    cvt_ln<<<20480, 256, 0, stream>>>(win, wout, w1, w2, wq_b, wo_b, w1_b, w2_b,
                                      x, n1w, n1b, xnb);
    // 2) QKV projection — grid 1536: BN=128
    gemm_bt<0, 128><<<(3 * D_ / 128) * (TOK_ / 128), 256, 0, stream>>>(
        xnb, wq_b, nullptr, nullptr, qkv, TOK_, 3 * D_, D_);
    // 3) attention — 1D XCD-pinned grid, mask in LDS, setprio on MFMA
    attn_kernel<<<(N_ / 64) * H_ * B_, 256, 0, stream>>>(
        qkv, qkv + (size_t)TOK_ * D_, qkv + (size_t)2 * TOK_ * D_, ids, attno);
    // 4) out projection + bias + residual(xn bf16) -> x1 bf16 — BN=64: grid 1024 (4 blk/CU)
    gemm_bt<3, 64><<<(D_ / 64) * (TOK_ / 128), 256, 0, stream>>>(
        attno, wo_b, bout, xnb, x1b, TOK_, D_, D_);
    // 5) LN2 (bf16 in -> bf16 out)
    lnb_kernel<<<TOK_, 256, 0, stream>>>(x1b, n2w, n2b, x2b);
    // 6) lin1 + bias + GELU — grid 2048: BN=128
    gemm_bt<2, 128><<<(FF_ / 128) * (TOK_ / 128), 256, 0, stream>>>(
        x2b, w1_b, b1, nullptr, hbuf, TOK_, FF_, D_);
    // 7) lin2 + bias + residual(x2 bf16) -> out fp32 — BN=64: grid 1024 (4 blk/CU)
    gemm_bt<1, 64><<<(D_ / 64) * (TOK_ / 128), 256, 0, stream>>>(
        hbuf, w2_b, b2, x2b, out, TOK_, D_, FF_);
}